// Round 4
// baseline (1860.507 us; speedup 1.0000x reference)
//
#include <hip/hip_runtime.h>
#include <math.h>

#define DIM   1024
#define NV    512
#define VD    256
#define NTOK  32768

// Output layout (floats): out | soft | perp | gumbel
#define SOFT_OFF  8388608u    // 32768*256
#define PERP_OFF  25165824u   // + 32768*512
#define GUM_OFF   25165825u   // + 1  (odd -> only 4B aligned!)

#define LO_SCALE      4096.0f
#define INV_LO_SCALE  (1.0f / 4096.0f)

typedef __attribute__((ext_vector_type(8)))  _Float16 half8;
typedef __attribute__((ext_vector_type(4)))  _Float16 half4;
typedef __attribute__((ext_vector_type(16))) float    float16v;

// d_ws layout: Whi (1MB) | Wlo (1MB) | sums (513 f32, pad to 4KB) | kidx (128KB)
#define WLO_ELEM_OFF  (NV * DIM)
#define SUMS_BYTE_OFF (2u * NV * DIM * 2u)
#define KIDX_BYTE_OFF (SUMS_BYTE_OFF + 4096u)

// ---------------------------------------------------------------------------
// K0: split W (fp32) into f16 hi plane + scaled f16 lo plane.
// ---------------------------------------------------------------------------
__global__ __launch_bounds__(256) void k_wsplit(const float* __restrict__ W,
                                                _Float16* __restrict__ whi,
                                                _Float16* __restrict__ wlo) {
    const int i = (blockIdx.x * 256 + threadIdx.x) * 4;
    float4 w = *(const float4*)(W + i);
    _Float16 h0 = (_Float16)w.x, h1 = (_Float16)w.y, h2 = (_Float16)w.z, h3 = (_Float16)w.w;
    _Float16 l0 = (_Float16)((w.x - (float)h0) * LO_SCALE);
    _Float16 l1 = (_Float16)((w.y - (float)h1) * LO_SCALE);
    _Float16 l2 = (_Float16)((w.z - (float)h2) * LO_SCALE);
    _Float16 l3 = (_Float16)((w.w - (float)h3) * LO_SCALE);
    *(half4*)(whi + i) = (half4){h0, h1, h2, h3};
    *(half4*)(wlo + i) = (half4){l0, l1, l2, l3};
}

// ---------------------------------------------------------------------------
// K1: logits = x @ W^T via split-precision f16 MFMA (32x32x16), 3 passes.
// Changes vs R3: XCD-aware swizzle (the 4 n-blocks of one m-stripe land on
// the SAME XCD so the x-stripe is fetched once per L2, reused 4x) and
// occupancy 2 -> 4 blocks/CU (LDS 40KB x 4 = 160KB, VGPR 96 <= 128).
// ---------------------------------------------------------------------------
#define BM 128
#define BN 128
#define BK 32
#define LSTR 40

__global__ __launch_bounds__(256, 4) void k_gemm_mfma(
        const float* __restrict__ x,
        const _Float16* __restrict__ whi,
        const _Float16* __restrict__ wlo,
        const float* __restrict__ mask,
        float* __restrict__ logits) {
    __shared__ _Float16 sAh[BM * LSTR];
    __shared__ _Float16 sAl[BM * LSTR];
    __shared__ _Float16 sBh[BN * LSTR];
    __shared__ _Float16 sBl[BN * LSTR];

    const int tid  = threadIdx.x;
    const int lane = tid & 63;
    const int wave = tid >> 6;
    const int wm = wave >> 1, wn = wave & 1;

    // XCD-aware swizzle: b%8 = XCD (measured m09). Give each XCD 32 m-stripes;
    // its 4 consecutive-on-XCD blocks sweep n for one m-stripe.
    const int b   = blockIdx.x;
    const int xcd = b & 7;
    const int j   = b >> 3;
    const int n0  = (j & 3) * BN;
    const int m0  = (xcd * 32 + (j >> 2)) * BM;

    const int lr = tid >> 1;
    const int kc = (tid & 1) * 16;

    float16v accM[2][2], accC[2][2];
#pragma unroll
    for (int i = 0; i < 2; ++i)
#pragma unroll
        for (int jj = 0; jj < 2; ++jj) {
            accM[i][jj] = (float16v)(0.0f);
            accC[i][jj] = (float16v)(0.0f);
        }

    const float*    aptr = x   + (size_t)(m0 + lr) * DIM + kc;
    const _Float16* bhp  = whi + (size_t)(n0 + lr) * DIM + kc;
    const _Float16* blp  = wlo + (size_t)(n0 + lr) * DIM + kc;

    const int lm = lane & 31;
    const int lk = (lane >> 5) * 8;

    for (int k0 = 0; k0 < DIM; k0 += BK) {
        float4 a0 = *(const float4*)(aptr + k0);
        float4 a1 = *(const float4*)(aptr + k0 + 4);
        float4 a2 = *(const float4*)(aptr + k0 + 8);
        float4 a3 = *(const float4*)(aptr + k0 + 12);
        uint4 bh0 = *(const uint4*)(bhp + k0);
        uint4 bh1 = *(const uint4*)(bhp + k0 + 8);
        uint4 bl0 = *(const uint4*)(blp + k0);
        uint4 bl1 = *(const uint4*)(blp + k0 + 8);

        __syncthreads();

        float fa[16] = {a0.x, a0.y, a0.z, a0.w, a1.x, a1.y, a1.z, a1.w,
                        a2.x, a2.y, a2.z, a2.w, a3.x, a3.y, a3.z, a3.w};
        _Float16 h[16], l[16];
#pragma unroll
        for (int q = 0; q < 16; ++q) {
            h[q] = (_Float16)fa[q];
            l[q] = (_Float16)((fa[q] - (float)h[q]) * LO_SCALE);
        }
        const int sbase = lr * LSTR + kc;
        *(half8*)&sAh[sbase]     = (half8){h[0], h[1], h[2], h[3], h[4], h[5], h[6], h[7]};
        *(half8*)&sAh[sbase + 8] = (half8){h[8], h[9], h[10], h[11], h[12], h[13], h[14], h[15]};
        *(half8*)&sAl[sbase]     = (half8){l[0], l[1], l[2], l[3], l[4], l[5], l[6], l[7]};
        *(half8*)&sAl[sbase + 8] = (half8){l[8], l[9], l[10], l[11], l[12], l[13], l[14], l[15]};
        *(uint4*)&sBh[sbase]     = bh0;
        *(uint4*)&sBh[sbase + 8] = bh1;
        *(uint4*)&sBl[sbase]     = bl0;
        *(uint4*)&sBl[sbase + 8] = bl1;

        __syncthreads();

#pragma unroll
        for (int hh = 0; hh < 2; ++hh) {
            const int koff = hh * 16 + lk;
            half8 ah[2], al[2], bh[2], bl[2];
#pragma unroll
            for (int t = 0; t < 2; ++t) {
                const int arow = wm * 64 + t * 32 + lm;
                ah[t] = *(half8*)&sAh[arow * LSTR + koff];
                al[t] = *(half8*)&sAl[arow * LSTR + koff];
                const int brow = wn * 64 + t * 32 + lm;
                bh[t] = *(half8*)&sBh[brow * LSTR + koff];
                bl[t] = *(half8*)&sBl[brow * LSTR + koff];
            }
#pragma unroll
            for (int ti = 0; ti < 2; ++ti)
#pragma unroll
                for (int tj = 0; tj < 2; ++tj) {
                    accM[ti][tj] = __builtin_amdgcn_mfma_f32_32x32x16_f16(ah[ti], bh[tj], accM[ti][tj], 0, 0, 0);
                    accC[ti][tj] = __builtin_amdgcn_mfma_f32_32x32x16_f16(ah[ti], bl[tj], accC[ti][tj], 0, 0, 0);
                    accC[ti][tj] = __builtin_amdgcn_mfma_f32_32x32x16_f16(al[ti], bh[tj], accC[ti][tj], 0, 0, 0);
                }
        }
    }

    const int lq = lane >> 5;
#pragma unroll
    for (int ti = 0; ti < 2; ++ti)
#pragma unroll
        for (int tj = 0; tj < 2; ++tj) {
            const int colbase = n0 + wn * 64 + tj * 32 + lm;
#pragma unroll
            for (int r = 0; r < 16; ++r) {
                const int row = wm * 64 + ti * 32 + (r & 3) + 8 * (r >> 2) + 4 * lq;
                const int m = m0 + row;
                float v = accM[ti][tj][r] + accC[ti][tj][r] * INV_LO_SCALE;
                v *= mask[m];
                if (colbase == 0) v = 0.0f;
                logits[(size_t)m * NV + colbase] = v;
            }
        }
}

// ---------------------------------------------------------------------------
// K2a: softmax+argmax over soft (in place) + kidx + fused masked colsums.
// 2 tokens per wave, 8 per block. Pure streaming besides shuffles.
// ---------------------------------------------------------------------------
__global__ __launch_bounds__(256) void k_smax(float* __restrict__ soft,
                                              const float* __restrict__ mask,
                                              float* __restrict__ sums,
                                              int* __restrict__ kidx) {
    __shared__ float scol[NV];
    const int tid  = threadIdx.x;
    const int lane = tid & 63;
    const int wave = tid >> 6;
    const int tblk = blockIdx.x * 8;
    const int t0   = tblk + wave * 2;

    scol[tid] = 0.f;
    scol[tid + 256] = 0.f;

    float4 u0[2], u1[2];
#pragma unroll
    for (int t = 0; t < 2; ++t) {
        const float* row = soft + (size_t)(t0 + t) * NV;
        u0[t] = *(const float4*)(row + lane * 4);
        u1[t] = *(const float4*)(row + 256 + lane * 4);
    }
    __syncthreads();

    float bm[2]; int bi[2];
#pragma unroll
    for (int t = 0; t < 2; ++t) {
        float v[8] = {u0[t].x, u0[t].y, u0[t].z, u0[t].w,
                      u1[t].x, u1[t].y, u1[t].z, u1[t].w};
        float m = v[0]; int ix = lane * 4;
#pragma unroll
        for (int jj = 1; jj < 8; ++jj) {
            const int col = (jj < 4) ? (lane * 4 + jj) : (256 + lane * 4 + (jj - 4));
            if (v[jj] > m) { m = v[jj]; ix = col; }
        }
        bm[t] = m; bi[t] = ix;
    }
#pragma unroll
    for (int off = 32; off > 0; off >>= 1)
#pragma unroll
        for (int t = 0; t < 2; ++t) {
            float om = __shfl_xor(bm[t], off, 64);
            int   oi = __shfl_xor(bi[t], off, 64);
            if (om > bm[t] || (om == bm[t] && oi < bi[t])) { bm[t] = om; bi[t] = oi; }
        }

    float s[2];
#pragma unroll
    for (int t = 0; t < 2; ++t) {
        u0[t].x = __expf(u0[t].x - bm[t]); u0[t].y = __expf(u0[t].y - bm[t]);
        u0[t].z = __expf(u0[t].z - bm[t]); u0[t].w = __expf(u0[t].w - bm[t]);
        u1[t].x = __expf(u1[t].x - bm[t]); u1[t].y = __expf(u1[t].y - bm[t]);
        u1[t].z = __expf(u1[t].z - bm[t]); u1[t].w = __expf(u1[t].w - bm[t]);
        s[t] = u0[t].x + u0[t].y + u0[t].z + u0[t].w
             + u1[t].x + u1[t].y + u1[t].z + u1[t].w;
    }
#pragma unroll
    for (int off = 32; off > 0; off >>= 1)
#pragma unroll
        for (int t = 0; t < 2; ++t) s[t] += __shfl_xor(s[t], off, 64);

#pragma unroll
    for (int t = 0; t < 2; ++t) {
        const int tok = t0 + t;
        const float inv = 1.f / s[t];
        const float mk = mask[tok];
        u0[t].x *= inv; u0[t].y *= inv; u0[t].z *= inv; u0[t].w *= inv;
        u1[t].x *= inv; u1[t].y *= inv; u1[t].z *= inv; u1[t].w *= inv;
        float* row = soft + (size_t)tok * NV;
        *(float4*)(row + lane * 4) = u0[t];
        *(float4*)(row + 256 + lane * 4) = u1[t];
        if (lane == 0) kidx[tok] = bi[t];

        atomicAdd(&scol[lane * 4 + 0], u0[t].x * mk);
        atomicAdd(&scol[lane * 4 + 1], u0[t].y * mk);
        atomicAdd(&scol[lane * 4 + 2], u0[t].z * mk);
        atomicAdd(&scol[lane * 4 + 3], u0[t].w * mk);
        atomicAdd(&scol[256 + lane * 4 + 0], u1[t].x * mk);
        atomicAdd(&scol[256 + lane * 4 + 1], u1[t].y * mk);
        atomicAdd(&scol[256 + lane * 4 + 2], u1[t].z * mk);
        atomicAdd(&scol[256 + lane * 4 + 3], u1[t].w * mk);
    }
    __syncthreads();
    atomicAdd(&sums[tid], scol[tid]);
    atomicAdd(&sums[tid + 256], scol[tid + 256]);

    if (wave == 0) {
        float mv = (lane < 8) ? mask[tblk + lane] : 0.f;
#pragma unroll
        for (int off = 32; off > 0; off >>= 1) mv += __shfl_xor(mv, off, 64);
        if (lane == 0) atomicAdd(&sums[NV], mv);
    }
}

// ---------------------------------------------------------------------------
// K2b: one-hot writer. Wave w writes 2 tokens; coalesced 256B scalar stores
// (gumbel base is odd -> 4B alignment only).
// ---------------------------------------------------------------------------
__global__ __launch_bounds__(256) void k_onehot(const int* __restrict__ kidx,
                                                float* __restrict__ gumbel) {
    const int lane = threadIdx.x & 63;
    const int wave = threadIdx.x >> 6;
    const int t0 = blockIdx.x * 8 + wave * 2;
#pragma unroll
    for (int t = 0; t < 2; ++t) {
        const int tok = t0 + t;
        const int k = kidx[tok];
        float* grow = gumbel + (size_t)tok * NV;
#pragma unroll
        for (int jj = 0; jj < 8; ++jj) {
            const int col = jj * 64 + lane;
            grow[col] = (col == k) ? 1.f : 0.f;
        }
    }
}

// ---------------------------------------------------------------------------
// K2c: codebook gather. Wave = 2 tokens, float4 loads/stores.
// ---------------------------------------------------------------------------
__global__ __launch_bounds__(256) void k_gather(const int* __restrict__ kidx,
                                                const float* __restrict__ codebook,
                                                float* __restrict__ outp) {
    const int lane = threadIdx.x & 63;
    const int wave = threadIdx.x >> 6;
    const int t0 = blockIdx.x * 8 + wave * 2;
#pragma unroll
    for (int t = 0; t < 2; ++t) {
        const int tok = t0 + t;
        const int k = kidx[tok];
        float4 cbv;
        if (k == 0) {
            cbv.x = cbv.y = cbv.z = cbv.w = 0.f;
        } else {
            cbv = *(const float4*)(codebook + (size_t)k * VD + lane * 4);
        }
        *(float4*)(outp + (size_t)tok * VD + lane * 4) = cbv;
    }
}

// ---------------------------------------------------------------------------
// K3: perplexity from 513 accumulated floats
// ---------------------------------------------------------------------------
__global__ __launch_bounds__(256) void k_perp(const float* __restrict__ sums,
                                              float* __restrict__ perp) {
    __shared__ float red[256];
    const int tid = threadIdx.x;
    const float msum = sums[NV];
    float ent = 0.f;
    for (int c = tid; c < NV; c += 256) {
        const float a = sums[c] / msum;
        ent += a * logf(a + 1e-7f);
    }
    red[tid] = ent;
    __syncthreads();
    for (int s = 128; s > 0; s >>= 1) {
        if (tid < s) red[tid] += red[tid + s];
        __syncthreads();
    }
    if (tid == 0) perp[0] = expf(-red[0]);
}

// ---------------------------------------------------------------------------
extern "C" void kernel_launch(void* const* d_in, const int* in_sizes, int n_in,
                              void* d_out, int out_size, void* d_ws, size_t ws_size,
                              hipStream_t stream) {
    const float* x    = (const float*)d_in[0];
    const float* mask = (const float*)d_in[1];
    const float* W    = (const float*)d_in[2];
    const float* cb   = (const float*)d_in[3];

    float* out    = (float*)d_out;
    float* soft   = out + SOFT_OFF;
    float* perp   = out + PERP_OFF;
    float* gumbel = out + GUM_OFF;

    _Float16* whi = (_Float16*)d_ws;
    _Float16* wlo = whi + WLO_ELEM_OFF;
    float* sums   = (float*)((char*)d_ws + SUMS_BYTE_OFF);
    int*   kidx   = (int*)((char*)d_ws + KIDX_BYTE_OFF);

    hipMemsetAsync(sums, 0, (NV + 1) * sizeof(float), stream);

    k_wsplit<<<NV * DIM / (256 * 4), 256, 0, stream>>>(W, whi, wlo);
    k_gemm_mfma<<<(NV / BN) * (NTOK / BM), 256, 0, stream>>>(x, whi, wlo, mask, soft);
    k_smax<<<NTOK / 8, 256, 0, stream>>>(soft, mask, sums, kidx);
    k_onehot<<<NTOK / 8, 256, 0, stream>>>(kidx, gumbel);
    k_gather<<<NTOK / 8, 256, 0, stream>>>(kidx, cb, out);
    k_perp<<<1, 256, 0, stream>>>(sums, perp);
}